// Round 15
// baseline (374.945 us; speedup 1.0000x reference)
//
#include <hip/hip_runtime.h>
#include <hip/hip_bf16.h>

#define NN 50000
#define EE 500000
#define GG 64
#define NSL 50        // dst slices (SPAN nodes each)
#define SPAN 1000
#define NCH 125       // edge chunks
#define EPG (EE / NCH)  // 4000
#define NCNT (4 * NSL * NCH)  // 25000
#define SCB ((NCNT + 255) / 256)  // 98 scan blocks

typedef __attribute__((ext_vector_type(8))) short bf16x8;
typedef __attribute__((ext_vector_type(4))) float f32x4;

__device__ __forceinline__ float wred_sum(float v) {
#pragma unroll
  for (int s = 32; s; s >>= 1) v += __shfl_xor(v, s, 64);
  return v;
}
// 16-lane group reductions (xor masks stay within the group)
__device__ __forceinline__ float gred_sum(float v) {
  v += __shfl_xor(v, 1, 64);
  v += __shfl_xor(v, 2, 64);
  v += __shfl_xor(v, 4, 64);
  v += __shfl_xor(v, 8, 64);
  return v;
}

__device__ __forceinline__ short f2bf(float x) {
  __hip_bfloat16 b = __float2bfloat16(x);
  return *reinterpret_cast<short*>(&b);
}
__device__ __forceinline__ float bf2f(unsigned short s) {
  __hip_bfloat16 b = *reinterpret_cast<__hip_bfloat16*>(&s);
  return __bfloat162float(b);
}

// ---- v = w_dst @ att_dst: one wave per output element (8*128 = 1024 waves) ----
__global__ __launch_bounds__(256) void v_kernel(const float* wdst, const float* adst, float* v) {
  int wv = (blockIdx.x * 256 + threadIdx.x) >> 6;  // 0..1023
  int lane = threadIdx.x & 63;
  int le = wv >> 7, k = wv & 127;
  const float* W = wdst + (size_t)le * 16384 + k * 128;
  const float* a = adst + le * 128;
  float p = W[lane] * a[lane] + W[64 + lane] * a[64 + lane];
  p = wred_sum(p);
  if (lane == 0) v[le * 128 + k] = p;
}

// ---- W convert: f32 [k][c] -> bf16 hi/lo transposed [c][k]; one element/thread ----
__global__ __launch_bounds__(256) void wcvt_kernel(const float* wsrc, short* whiT, short* wloT) {
  int idx = blockIdx.x * 256 + threadIdx.x;  // 0..131071
  int le = idx >> 14, rem = idx & 16383;
  int c = rem >> 7, k = rem & 127;
  float v = wsrc[(size_t)le * 16384 + k * 128 + c];
  short hi = f2bf(v);
  whiT[idx] = hi;
  wloT[idx] = f2bf(v - bf2f((unsigned short)hi));
}

// ======== CSR build: radix partition by dst slice, then per-slice build ========

__global__ __launch_bounds__(256) void pcount_kernel(const int* e0, const int* e1, const int* e2,
                                                     const int* e3, int* counts) {
  int t = blockIdx.y, ch = blockIdx.x;
  const int* ei = (t == 0 ? e0 : t == 1 ? e1 : t == 2 ? e2 : e3);
  const int* dst = ei + EE;
  __shared__ int cnt[NSL];
  for (int i = threadIdx.x; i < NSL; i += 256) cnt[i] = 0;
  __syncthreads();
  int i0 = ch * EPG;
  for (int i = i0 + threadIdx.x; i < i0 + EPG; i += 256) atomicAdd(&cnt[dst[i] / SPAN], 1);
  __syncthreads();
  for (int sl = threadIdx.x; sl < NSL; sl += 256) counts[(t * NSL + sl) * NCH + ch] = cnt[sl];
}

// ---- hierarchical exclusive scan over counts[NCNT] ----
__global__ __launch_bounds__(256) void scan1_kernel(const int* counts, int* bsums) {
  int tid = threadIdx.x, lane = tid & 63, wid = tid >> 6;
  int idx = blockIdx.x * 256 + tid;
  int v = (idx < NCNT) ? counts[idx] : 0;
#pragma unroll
  for (int s = 32; s; s >>= 1) v += __shfl_xor(v, s, 64);
  __shared__ int ws[4];
  if (lane == 0) ws[wid] = v;
  __syncthreads();
  if (tid == 0) bsums[blockIdx.x] = ws[0] + ws[1] + ws[2] + ws[3];
}

__global__ void scan2_kernel(int* bsums) {
  __shared__ int s[SCB];
  int tid = threadIdx.x;
  if (tid < SCB) s[tid] = bsums[tid];
  __syncthreads();
  if (tid == 0) {
    int run = 0;
    for (int i = 0; i < SCB; i++) { int x = s[i]; s[i] = run; run += x; }
  }
  __syncthreads();
  if (tid < SCB) bsums[tid] = s[tid];
}

__global__ __launch_bounds__(256) void scan3_kernel(int* counts, const int* bsums, int* sliceptr) {
  int tid = threadIdx.x, lane = tid & 63, wid = tid >> 6;
  int idx = blockIdx.x * 256 + tid;
  int v = (idx < NCNT) ? counts[idx] : 0;
  int orig = v;
#pragma unroll
  for (int s = 1; s < 64; s <<= 1) { int u = __shfl_up(v, s, 64); if (lane >= s) v += u; }
  __shared__ int ws[4];
  if (lane == 63) ws[wid] = v;
  __syncthreads();
  int woff = (wid > 0 ? ws[0] : 0) + (wid > 1 ? ws[1] : 0) + (wid > 2 ? ws[2] : 0);
  int excl = bsums[blockIdx.x] + woff + v - orig;
  if (idx < NCNT) {
    counts[idx] = excl;
    if (idx % NCH == 0) {
      int g = idx / NCH;  // 0..199 = t*NSL + slice
      sliceptr[(g / NSL) * (NSL + 1) + (g % NSL)] = excl;
    }
  }
  if (blockIdx.x == 0 && tid < 4) sliceptr[tid * (NSL + 1) + NSL] = (tid + 1) * EE;
}

__global__ __launch_bounds__(256) void ppart_kernel(const int* e0, const int* e1, const int* e2,
                                                    const int* e3, const int* counts, int2* pairs) {
  int t = blockIdx.y, ch = blockIdx.x;
  const int* ei = (t == 0 ? e0 : t == 1 ? e1 : t == 2 ? e2 : e3);
  const int* srcr = ei;
  const int* dstr = ei + EE;
  __shared__ int cur[NSL];
  for (int i = threadIdx.x; i < NSL; i += 256) cur[i] = counts[(t * NSL + i) * NCH + ch];
  __syncthreads();
  int i0 = ch * EPG;
  for (int i = i0 + threadIdx.x; i < i0 + EPG; i += 256) {
    int d = dstr[i], s = srcr[i];
    int pos = atomicAdd(&cur[d / SPAN], 1);
    pairs[pos] = make_int2(s, d);
  }
}

__global__ __launch_bounds__(256) void pbuild_kernel(const int2* pairs, const int* sliceptr,
                                                     int* rowptr, int* col) {
  int t = blockIdx.y, sl = blockIdx.x;
  int n0 = sl * SPAN;
  int e0 = sliceptr[t * (NSL + 1) + sl], e1 = sliceptr[t * (NSL + 1) + sl + 1];
  int tid = threadIdx.x, lane = tid & 63, wid = tid >> 6;
  __shared__ int cnt[SPAN];
  __shared__ int wsum[4];
  for (int i = tid; i < SPAN; i += 256) cnt[i] = 0;
  __syncthreads();
  for (int e = e0 + tid; e < e1; e += 256) atomicAdd(&cnt[pairs[e].y - n0], 1);
  __syncthreads();
  int s0 = 0, s1 = 0, s2 = 0, s3 = 0, tot = 0;
  if (tid < SPAN / 4) {
    s0 = cnt[tid * 4]; s1 = cnt[tid * 4 + 1]; s2 = cnt[tid * 4 + 2]; s3 = cnt[tid * 4 + 3];
    tot = s0 + s1 + s2 + s3;
  }
  int v = tot;
#pragma unroll
  for (int sft = 1; sft < 64; sft <<= 1) { int u = __shfl_up(v, sft, 64); if (lane >= sft) v += u; }
  if (lane == 63) wsum[wid] = v;
  __syncthreads();
  int woffv = (wid > 0 ? wsum[0] : 0) + (wid > 1 ? wsum[1] : 0) + (wid > 2 ? wsum[2] : 0);
  int excl = v + woffv - tot;
  __syncthreads();
  if (tid < SPAN / 4) {
    cnt[tid * 4] = excl;
    cnt[tid * 4 + 1] = excl + s0;
    cnt[tid * 4 + 2] = excl + s0 + s1;
    cnt[tid * 4 + 3] = excl + s0 + s1 + s2;
  }
  __syncthreads();
  int base = e0 - t * EE;
  for (int n = tid; n < SPAN; n += 256) rowptr[(size_t)t * (NN + 1) + n0 + n] = base + cnt[n];
  if (sl == NSL - 1 && tid == 0) rowptr[(size_t)t * (NN + 1) + NN] = EE;
  __syncthreads();
  int* ct = col + (size_t)t * EE;
  for (int e = e0 + tid; e < e1; e += 256) {
    int2 p = pairs[e];
    int pos = base + atomicAdd(&cnt[p.y - n0], 1);
    ct[pos] = p.x;
  }
}

// ---- graph boundaries via binary search on sorted batch vectors ----
__global__ void gbound_kernel(const int* batchA, const int* batchB, int* gbA, int* gbB) {
  int t = threadIdx.x;
  if (t >= 130) return;
  int which = t / 65, g = t % 65;
  const int* b = which ? batchB : batchA;
  int* gb = which ? gbB : gbA;
  int lo = 0, hi = NN;
  while (lo < hi) { int mid = (lo + hi) >> 1; if (b[mid] < g) lo = mid + 1; else hi = mid; }
  gb[g] = lo;
}

// ---- MFMA GEMM h = X @ W (split-bf16, 3 terms), z=4, register-prefetch pipelined ----
#define SWZ(row, kb) ((((row) << 6) + (kb)) ^ (((row) & 7) << 4))
#define HSTRIDE 136   // 272B = 17x16B: keeps epilogue rows 16B-aligned (no split reads)

__device__ __forceinline__ void cvt8(const float4 a, const float4 b, bf16x8& hv, bf16x8& lv) {
  short h;
  h = f2bf(a.x); hv[0] = h; lv[0] = f2bf(a.x - bf2f((unsigned short)h));
  h = f2bf(a.y); hv[1] = h; lv[1] = f2bf(a.y - bf2f((unsigned short)h));
  h = f2bf(a.z); hv[2] = h; lv[2] = f2bf(a.z - bf2f((unsigned short)h));
  h = f2bf(a.w); hv[3] = h; lv[3] = f2bf(a.w - bf2f((unsigned short)h));
  h = f2bf(b.x); hv[4] = h; lv[4] = f2bf(b.x - bf2f((unsigned short)h));
  h = f2bf(b.y); hv[5] = h; lv[5] = f2bf(b.y - bf2f((unsigned short)h));
  h = f2bf(b.z); hv[6] = h; lv[6] = f2bf(b.z - bf2f((unsigned short)h));
  h = f2bf(b.w); hv[7] = h; lv[7] = f2bf(b.w - bf2f((unsigned short)h));
}

__global__ __launch_bounds__(256) void gemm_hs_kernel(
    const float* X0_, const float* X1_,
    const short* whiT, const short* wloT,   // pre-offset by L*4*16384
    const float* attsrc,                    // pre-offset by L*4*128
    unsigned short* h4, float* s4) {
  int e = blockIdx.z;
  const float* X = (e < 2) ? X0_ : X1_;   // EDGE_TYPES: e0,e1 src=A; e2,e3 src=B
  const short* Wh = whiT + (size_t)e * 16384;
  const short* Wl = wloT + (size_t)e * 16384;
  const float* att = attsrc + e * 128;
  unsigned short* h = h4 + (size_t)e * NN * 128;
  float* s_ = s4 + (size_t)e * NN;

  // 32KB pool: 4 staging planes (16384 shorts); epilogue reuses it as a 64x136 half-tile
  __shared__ short smem[16384];
  short* Ah = smem;
  short* Al = smem + 4096;
  short* Bh = smem + 8192;
  short* Bl = smem + 12288;

  int tid = threadIdx.x;
  int l = tid & 63, w = tid >> 6;
  int arow = l & 15;
  int kb = (l >> 4) << 4;
  int row0 = blockIdx.x * 128;

  f32x4 acc[2][8];
#pragma unroll
  for (int i = 0; i < 2; i++)
#pragma unroll
    for (int j = 0; j < 8; j++) acc[i][j] = (f32x4){0.f, 0.f, 0.f, 0.f};

  float attr[8];
#pragma unroll
  for (int j = 0; j < 8; j++) attr[j] = att[j * 16 + arow];

  int sr = tid >> 1, half = tid & 1;
  int xrow = row0 + sr; xrow = xrow < NN ? xrow : NN - 1;
  const float* xbase = X + (size_t)xrow * 128 + half * 16;
  const short* whbase = Wh + sr * 128 + half * 16;
  const short* wlbase = Wl + sr * 128 + half * 16;
  int soff0 = SWZ(sr, half * 32);
  int soff1 = SWZ(sr, half * 32 + 16);

  // prologue: load tile kt=0 into registers
  float4 f0 = *(const float4*)(xbase);
  float4 f1 = *(const float4*)(xbase + 4);
  float4 f2 = *(const float4*)(xbase + 8);
  float4 f3 = *(const float4*)(xbase + 12);
  bf16x8 wh0 = *(const bf16x8*)(whbase);
  bf16x8 wh1 = *(const bf16x8*)(whbase + 8);
  bf16x8 wl0 = *(const bf16x8*)(wlbase);
  bf16x8 wl1 = *(const bf16x8*)(wlbase + 8);

  for (int kt = 0; kt < 128; kt += 32) {
    // stage current registers -> LDS
    bf16x8 hv0, lv0, hv1, lv1;
    cvt8(f0, f1, hv0, lv0);
    cvt8(f2, f3, hv1, lv1);
    *(bf16x8*)((char*)Ah + soff0) = hv0;
    *(bf16x8*)((char*)Ah + soff1) = hv1;
    *(bf16x8*)((char*)Al + soff0) = lv0;
    *(bf16x8*)((char*)Al + soff1) = lv1;
    *(bf16x8*)((char*)Bh + soff0) = wh0;
    *(bf16x8*)((char*)Bh + soff1) = wh1;
    *(bf16x8*)((char*)Bl + soff0) = wl0;
    *(bf16x8*)((char*)Bl + soff1) = wl1;
    __syncthreads();

    // issue next tile's global loads (latency hides under MFMA below)
    if (kt < 96) {
      f0 = *(const float4*)(xbase + kt + 32);
      f1 = *(const float4*)(xbase + kt + 36);
      f2 = *(const float4*)(xbase + kt + 40);
      f3 = *(const float4*)(xbase + kt + 44);
      wh0 = *(const bf16x8*)(whbase + kt + 32);
      wh1 = *(const bf16x8*)(whbase + kt + 40);
      wl0 = *(const bf16x8*)(wlbase + kt + 32);
      wl1 = *(const bf16x8*)(wlbase + kt + 40);
    }

    bf16x8 ah[2], al[2];
#pragma unroll
    for (int i = 0; i < 2; i++) {
      int row = w * 32 + i * 16 + arow;
      ah[i] = *(bf16x8*)((char*)Ah + SWZ(row, kb));
      al[i] = *(bf16x8*)((char*)Al + SWZ(row, kb));
    }
#pragma unroll
    for (int j = 0; j < 8; j++) {
      int colr = j * 16 + arow;
      bf16x8 bh = *(bf16x8*)((char*)Bh + SWZ(colr, kb));
      bf16x8 bl = *(bf16x8*)((char*)Bl + SWZ(colr, kb));
#pragma unroll
      for (int i = 0; i < 2; i++) {
        acc[i][j] = __builtin_amdgcn_mfma_f32_16x16x32_bf16(ah[i], bh, acc[i][j], 0, 0, 0);
        acc[i][j] = __builtin_amdgcn_mfma_f32_16x16x32_bf16(ah[i], bl, acc[i][j], 0, 0, 0);
        acc[i][j] = __builtin_amdgcn_mfma_f32_16x16x32_bf16(al[i], bh, acc[i][j], 0, 0, 0);
      }
    }
    __syncthreads();
  }

  // epilogue in two 64-row phases (64x136 tile fits inside the 32KB staging pool):
  // waves 0,1 own rows 0..63; waves 2,3 own rows 64..127.
#pragma unroll
  for (int p = 0; p < 2; p++) {
    if ((w >> 1) == p) {
#pragma unroll
      for (int i = 0; i < 2; i++) {
#pragma unroll
        for (int r = 0; r < 4; r++) {
          int lrow = (w & 1) * 32 + i * 16 + ((l >> 4) << 2) + r;  // 0..63
          int row = row0 + p * 64 + lrow;
          float pp = 0.f;
#pragma unroll
          for (int j = 0; j < 8; j++) pp += acc[i][j][r] * attr[j];
          pp += __shfl_xor(pp, 1, 64);
          pp += __shfl_xor(pp, 2, 64);
          pp += __shfl_xor(pp, 4, 64);
          pp += __shfl_xor(pp, 8, 64);
          if (row < NN && arow == 0) s_[row] = pp;
#pragma unroll
          for (int j = 0; j < 8; j++) smem[lrow * HSTRIDE + j * 16 + arow] = f2bf(acc[i][j][r]);
        }
      }
    }
    __syncthreads();
#pragma unroll
    for (int it = 0; it < 4; it++) {
      int idx = it * 256 + tid;  // 0..1023 -> (lrow 0..63, 16B chunk)
      int lrow = idx >> 4, c8 = idx & 15;
      int row = row0 + p * 64 + lrow;
      if (row < NN)
        *(bf16x8*)(h + (size_t)row * 128 + c8 * 8) = *(const bf16x8*)(smem + lrow * HSTRIDE + c8 * 8);
    }
    __syncthreads();
  }
}

#define ACC8(a, uv, wv)                             \
  do {                                              \
    a[0] += wv * __uint_as_float(uv.x << 16);       \
    a[1] += wv * __uint_as_float(uv.x & 0xffff0000u); \
    a[2] += wv * __uint_as_float(uv.y << 16);       \
    a[3] += wv * __uint_as_float(uv.y & 0xffff0000u); \
    a[4] += wv * __uint_as_float(uv.z << 16);       \
    a[5] += wv * __uint_as_float(uv.z & 0xffff0000u); \
    a[6] += wv * __uint_as_float(uv.w << 16);       \
    a[7] += wv * __uint_as_float(uv.w & 0xffff0000u); \
  } while (0)

// ---- per-dst-node GAT aggregation: TWO 16-lane groups per node (one per edge type);
//      single pass (exp(s) directly), 4-wide gather unroll, cross-group combine ----
__global__ __launch_bounds__(256) void agg_kernel(
    const float* xdst,
    const int* rpA, const int* colA, const unsigned short* hA_, const float* sA_, const float* vA, const float* bA,
    const int* rpB, const int* colB, const unsigned short* hB_, const float* sB_, const float* vB, const float* bB,
    float* Y) {
  int lane = threadIdx.x & 63;
  int q = lane & 15;             // lane within group
  int gb = lane & 48;            // group base within wave (for shfl)
  int t = (lane >> 4) & 1;       // group parity -> edge type half
  int node = blockIdx.x * 8 + (threadIdx.x >> 5);
  if (node >= NN) return;
  int d0 = q * 8;
  const float* xr = xdst + (size_t)node * 128 + d0;
  float4 xv0 = *(const float4*)(xr);
  float4 xv1 = *(const float4*)(xr + 4);

  const int* rp = t ? rpB : rpA;
  const int* cl = t ? colB : colA;
  const unsigned short* h = t ? hB_ : hA_;
  const float* ss = t ? sB_ : sA_;
  const float* v = t ? vB : vA;
  const float* b = t ? bB : bA;
  const uint4* hq = (const uint4*)h + q;  // lane's 16B slice of each row

  float4 v0 = *(const float4*)(v + d0);
  float4 v1 = *(const float4*)(v + d0 + 4);
  float part = xv0.x * v0.x + xv0.y * v0.y + xv0.z * v0.z + xv0.w * v0.w +
               xv1.x * v1.x + xv1.y * v1.y + xv1.z * v1.z + xv1.w * v1.w;
  float sd = gred_sum(part);

  int start = rp[node], end = rp[node + 1];
  int deg = end - start;

  float dsum = 0.f;
  float a[8] = {0.f, 0.f, 0.f, 0.f, 0.f, 0.f, 0.f, 0.f};

  for (int base2 = start; base2 < end; base2 += 16) {
    int i = base2 + q;
    int src = 0;
    float ex = 0.f;
    if (i < end) {
      src = cl[i];
      float s = ss[src] + sd;
      s = (s >= 0.f) ? s : 0.2f * s;
      ex = __expf(s);
    }
    dsum += ex;
    int cT = min(16, end - base2);
    int j = 0;
    for (; j + 3 < cT; j += 4) {
      int sj0 = __shfl(src, gb + j, 64);     float e0 = __shfl(ex, gb + j, 64);
      int sj1 = __shfl(src, gb + j + 1, 64); float e1 = __shfl(ex, gb + j + 1, 64);
      int sj2 = __shfl(src, gb + j + 2, 64); float e2 = __shfl(ex, gb + j + 2, 64);
      int sj3 = __shfl(src, gb + j + 3, 64); float e3 = __shfl(ex, gb + j + 3, 64);
      uint4 uv0 = hq[(size_t)sj0 * 16];
      uint4 uv1 = hq[(size_t)sj1 * 16];
      uint4 uv2 = hq[(size_t)sj2 * 16];
      uint4 uv3 = hq[(size_t)sj3 * 16];
      ACC8(a, uv0, e0);
      ACC8(a, uv1, e1);
      ACC8(a, uv2, e2);
      ACC8(a, uv3, e3);
    }
    for (; j < cT; j++) {
      int sj = __shfl(src, gb + j, 64);
      float ej = __shfl(ex, gb + j, 64);
      uint4 uv = hq[(size_t)sj * 16];
      ACC8(a, uv, ej);
    }
  }

  float denom = gred_sum(dsum);
  float inv = (deg > 0) ? 0.5f / (denom * (float)deg) : 0.f;
  float outv[8];
#pragma unroll
  for (int k2 = 0; k2 < 8; k2++) outv[k2] = a[k2] * inv + 0.5f * b[d0 + k2];

  // combine the two edge-type groups of this node (lanes x and x^16)
#pragma unroll
  for (int k2 = 0; k2 < 8; k2++) outv[k2] += __shfl_xor(outv[k2], 16, 64);

  if (!(lane & 16)) {
    float4 o0 = make_float4(fmaxf(outv[0], 0.f), fmaxf(outv[1], 0.f), fmaxf(outv[2], 0.f), fmaxf(outv[3], 0.f));
    float4 o1 = make_float4(fmaxf(outv[4], 0.f), fmaxf(outv[5], 0.f), fmaxf(outv[6], 0.f), fmaxf(outv[7], 0.f));
    *(float4*)(Y + (size_t)node * 128 + d0) = o0;
    *(float4*)(Y + (size_t)node * 128 + d0 + 4) = o1;
  }
}

// ---- mean pooling stage 1: partial sums, 8 chunks per (graph, type) ----
__global__ __launch_bounds__(128) void pool_part_kernel(const float* XA_, const float* XB_,
                                                        const int* gbA, const int* gbB,
                                                        float* pooled) {
  int t = blockIdx.y, g = blockIdx.x, c = blockIdx.z;
  const float* X = t ? XB_ : XA_;
  const int* gb = t ? gbB : gbA;
  int n0 = gb[g], n1 = gb[g + 1];
  int dim = threadIdx.x;  // 0..127
  float s = 0.f;
  for (int node = n0 + c; node < n1; node += 8) s += X[(size_t)node * 128 + dim];
  atomicAdd(&pooled[g * 256 + t * 128 + dim], s);
}

// ---- final linear (divides pooled sums by counts) ----
__global__ void final_kernel(const float* pooled, const int* gbA, const int* gbB,
                             const float* wc, const float* bc, float* out) {
  int tid = blockIdx.x * blockDim.x + threadIdx.x;
  if (tid >= GG * 10) return;
  int g = tid / 10, o = tid % 10;
  float invA = 1.f / fmaxf((float)(gbA[g + 1] - gbA[g]), 1.f);
  float invB = 1.f / fmaxf((float)(gbB[g + 1] - gbB[g]), 1.f);
  float acc = bc[o];
  for (int k = 0; k < 256; k++)
    acc += pooled[g * 256 + k] * (k < 128 ? invA : invB) * wc[k * 10 + o];
  out[g * 10 + o] = acc;
}

extern "C" void kernel_launch(void* const* d_in, const int* in_sizes, int n_in,
                              void* d_out, int out_size, void* d_ws, size_t ws_size,
                              hipStream_t stream) {
  const float* xA = (const float*)d_in[0];
  const float* xB = (const float*)d_in[1];
  const int* ei0 = (const int*)d_in[2];
  const int* ei1 = (const int*)d_in[3];
  const int* ei2 = (const int*)d_in[4];
  const int* ei3 = (const int*)d_in[5];
  const int* batchA = (const int*)d_in[6];
  const int* batchB = (const int*)d_in[7];
  const float* wsrc = (const float*)d_in[9];
  const float* wdst = (const float*)d_in[10];
  const float* attsrc = (const float*)d_in[11];
  const float* attdst = (const float*)d_in[12];
  const float* cbias = (const float*)d_in[13];
  const float* wc = (const float*)d_in[14];
  const float* bc = (const float*)d_in[15];
  float* out = (float*)d_out;

  char* ws = (char*)d_ws;
  size_t off = 0;
  auto alloc = [&](size_t bytes) { size_t o = off; off += (bytes + 255) & ~(size_t)255; return o; };
  size_t o_rowptr = alloc((size_t)4 * (NN + 1) * 4);
  size_t o_col    = alloc((size_t)4 * EE * 4);
  size_t o_cnts   = alloc((size_t)NCNT * 4);
  size_t o_bsums  = alloc((size_t)SCB * 4);
  size_t o_slptr  = alloc((size_t)4 * (NSL + 1) * 4);
  size_t o_v      = alloc((size_t)8 * 128 * 4);
  size_t o_whiT   = alloc((size_t)8 * 16384 * 2);
  size_t o_wloT   = alloc((size_t)8 * 16384 * 2);
  size_t o_h4     = alloc((size_t)4 * NN * 128 * 2);  // bf16 h per edge type; pairs alias pre-GEMM
  size_t o_s4     = alloc((size_t)4 * NN * 4);
  size_t o_Xa1    = alloc((size_t)NN * 128 * 4);
  size_t o_Xb1    = alloc((size_t)NN * 128 * 4);
  size_t o_Xa2    = alloc((size_t)NN * 128 * 4);
  size_t o_Xb2    = alloc((size_t)NN * 128 * 4);
  size_t o_pooled = alloc((size_t)GG * 256 * 4);
  size_t o_gb     = alloc((size_t)2 * (GG + 1) * 4);

  int* rowptr = (int*)(ws + o_rowptr);
  int* col = (int*)(ws + o_col);
  int* counts = (int*)(ws + o_cnts);
  int* bsums = (int*)(ws + o_bsums);
  int* sliceptr = (int*)(ws + o_slptr);
  float* vv = (float*)(ws + o_v);
  short* whiT = (short*)(ws + o_whiT);
  short* wloT = (short*)(ws + o_wloT);
  unsigned short* h4 = (unsigned short*)(ws + o_h4);
  float* s4 = (float*)(ws + o_s4);
  int2* pairs = (int2*)(ws + o_h4);  // 16 MB alias over h4 (dead until GEMMs)
  float* Xa1 = (float*)(ws + o_Xa1);
  float* Xb1 = (float*)(ws + o_Xb1);
  float* Xa2 = (float*)(ws + o_Xa2);
  float* Xb2 = (float*)(ws + o_Xb2);
  float* pooled = (float*)(ws + o_pooled);
  int* gbA = (int*)(ws + o_gb);
  int* gbB = gbA + (GG + 1);

  hipMemsetAsync(pooled, 0, (size_t)GG * 256 * 4, stream);

  v_kernel<<<256, 256, 0, stream>>>(wdst, attdst, vv);
  wcvt_kernel<<<512, 256, 0, stream>>>(wsrc, whiT, wloT);
  gbound_kernel<<<1, 192, 0, stream>>>(batchA, batchB, gbA, gbB);
  pcount_kernel<<<dim3(NCH, 4), 256, 0, stream>>>(ei0, ei1, ei2, ei3, counts);
  scan1_kernel<<<SCB, 256, 0, stream>>>(counts, bsums);
  scan2_kernel<<<1, 128, 0, stream>>>(bsums);
  scan3_kernel<<<SCB, 256, 0, stream>>>(counts, bsums, sliceptr);
  ppart_kernel<<<dim3(NCH, 4), 256, 0, stream>>>(ei0, ei1, ei2, ei3, counts, pairs);
  pbuild_kernel<<<dim3(NSL, 4), 256, 0, stream>>>(pairs, sliceptr, rowptr, col);

  int gemm_gx = (NN + 127) / 128;
  int agg_gx = (NN + 7) / 8;

  for (int L = 0; L < 2; L++) {
    const float* X0 = (L == 0) ? xA : Xa1;
    const float* X1 = (L == 0) ? xB : Xb1;
    float* Y0 = (L == 0) ? Xa1 : Xa2;
    float* Y1 = (L == 0) ? Xb1 : Xb2;

    // all 4 edge-type GEMMs of this layer in one z=4 launch
    gemm_hs_kernel<<<dim3(gemm_gx, 1, 4), 256, 0, stream>>>(
        X0, X1, whiT + (size_t)L * 4 * 16384, wloT + (size_t)L * 4 * 16384,
        attsrc + L * 4 * 128, h4, s4);

    // dst type 0: edge types 0 (src=A) and 2 (src=B)
    agg_kernel<<<agg_gx, 256, 0, stream>>>(
        X0,
        rowptr + (size_t)0 * (NN + 1), col + (size_t)0 * EE, h4 + (size_t)0 * NN * 128, s4 + (size_t)0 * NN,
        vv + (L * 4 + 0) * 128, cbias + (L * 4 + 0) * 128,
        rowptr + (size_t)2 * (NN + 1), col + (size_t)2 * EE, h4 + (size_t)2 * NN * 128, s4 + (size_t)2 * NN,
        vv + (L * 4 + 2) * 128, cbias + (L * 4 + 2) * 128,
        Y0);

    // dst type 1: edge types 1 (src=A) and 3 (src=B)
    agg_kernel<<<agg_gx, 256, 0, stream>>>(
        X1,
        rowptr + (size_t)1 * (NN + 1), col + (size_t)1 * EE, h4 + (size_t)1 * NN * 128, s4 + (size_t)1 * NN,
        vv + (L * 4 + 1) * 128, cbias + (L * 4 + 1) * 128,
        rowptr + (size_t)3 * (NN + 1), col + (size_t)3 * EE, h4 + (size_t)3 * NN * 128, s4 + (size_t)3 * NN,
        vv + (L * 4 + 3) * 128, cbias + (L * 4 + 3) * 128,
        Y1);
  }

  pool_part_kernel<<<dim3(GG, 2, 8), 128, 0, stream>>>(Xa2, Xb2, gbA, gbB, pooled);
  final_kernel<<<3, 256, 0, stream>>>(pooled, gbA, gbB, wc, bc, out);
}

// Round 16
// 363.571 us; speedup vs baseline: 1.0313x; 1.0313x over previous
//
#include <hip/hip_runtime.h>
#include <hip/hip_bf16.h>

#define NN 50000
#define EE 500000
#define GG 64
#define NSL 50        // dst slices (SPAN nodes each)
#define SPAN 1000
#define NCH 125       // edge chunks
#define EPG (EE / NCH)  // 4000
#define NCNT (4 * NSL * NCH)  // 25000
#define SCB ((NCNT + 255) / 256)  // 98 scan blocks

typedef __attribute__((ext_vector_type(8))) short bf16x8;
typedef __attribute__((ext_vector_type(4))) float f32x4;

__device__ __forceinline__ float wred_sum(float v) {
#pragma unroll
  for (int s = 32; s; s >>= 1) v += __shfl_xor(v, s, 64);
  return v;
}
// 16-lane group reductions (xor masks stay within the group)
__device__ __forceinline__ float gred_sum(float v) {
  v += __shfl_xor(v, 1, 64);
  v += __shfl_xor(v, 2, 64);
  v += __shfl_xor(v, 4, 64);
  v += __shfl_xor(v, 8, 64);
  return v;
}

__device__ __forceinline__ short f2bf(float x) {
  __hip_bfloat16 b = __float2bfloat16(x);
  return *reinterpret_cast<short*>(&b);
}
__device__ __forceinline__ float bf2f(unsigned short s) {
  __hip_bfloat16 b = *reinterpret_cast<__hip_bfloat16*>(&s);
  return __bfloat162float(b);
}

// ---- v = w_dst @ att_dst: one wave per output element (8*128 = 1024 waves) ----
__global__ __launch_bounds__(256) void v_kernel(const float* wdst, const float* adst, float* v) {
  int wv = (blockIdx.x * 256 + threadIdx.x) >> 6;  // 0..1023
  int lane = threadIdx.x & 63;
  int le = wv >> 7, k = wv & 127;
  const float* W = wdst + (size_t)le * 16384 + k * 128;
  const float* a = adst + le * 128;
  float p = W[lane] * a[lane] + W[64 + lane] * a[64 + lane];
  p = wred_sum(p);
  if (lane == 0) v[le * 128 + k] = p;
}

// ---- W convert: f32 [k][c] -> bf16 hi/lo transposed [c][k]; one element/thread ----
__global__ __launch_bounds__(256) void wcvt_kernel(const float* wsrc, short* whiT, short* wloT) {
  int idx = blockIdx.x * 256 + threadIdx.x;  // 0..131071
  int le = idx >> 14, rem = idx & 16383;
  int c = rem >> 7, k = rem & 127;
  float v = wsrc[(size_t)le * 16384 + k * 128 + c];
  short hi = f2bf(v);
  whiT[idx] = hi;
  wloT[idx] = f2bf(v - bf2f((unsigned short)hi));
}

// ======== CSR build: radix partition by dst slice, then per-slice build ========

__global__ __launch_bounds__(256) void pcount_kernel(const int* e0, const int* e1, const int* e2,
                                                     const int* e3, int* counts) {
  int t = blockIdx.y, ch = blockIdx.x;
  const int* ei = (t == 0 ? e0 : t == 1 ? e1 : t == 2 ? e2 : e3);
  const int* dst = ei + EE;
  __shared__ int cnt[NSL];
  for (int i = threadIdx.x; i < NSL; i += 256) cnt[i] = 0;
  __syncthreads();
  int i0 = ch * EPG;
  for (int i = i0 + threadIdx.x; i < i0 + EPG; i += 256) atomicAdd(&cnt[dst[i] / SPAN], 1);
  __syncthreads();
  for (int sl = threadIdx.x; sl < NSL; sl += 256) counts[(t * NSL + sl) * NCH + ch] = cnt[sl];
}

// ---- hierarchical exclusive scan over counts[NCNT] ----
__global__ __launch_bounds__(256) void scan1_kernel(const int* counts, int* bsums) {
  int tid = threadIdx.x, lane = tid & 63, wid = tid >> 6;
  int idx = blockIdx.x * 256 + tid;
  int v = (idx < NCNT) ? counts[idx] : 0;
#pragma unroll
  for (int s = 32; s; s >>= 1) v += __shfl_xor(v, s, 64);
  __shared__ int ws[4];
  if (lane == 0) ws[wid] = v;
  __syncthreads();
  if (tid == 0) bsums[blockIdx.x] = ws[0] + ws[1] + ws[2] + ws[3];
}

__global__ void scan2_kernel(int* bsums) {
  __shared__ int s[SCB];
  int tid = threadIdx.x;
  if (tid < SCB) s[tid] = bsums[tid];
  __syncthreads();
  if (tid == 0) {
    int run = 0;
    for (int i = 0; i < SCB; i++) { int x = s[i]; s[i] = run; run += x; }
  }
  __syncthreads();
  if (tid < SCB) bsums[tid] = s[tid];
}

__global__ __launch_bounds__(256) void scan3_kernel(int* counts, const int* bsums, int* sliceptr) {
  int tid = threadIdx.x, lane = tid & 63, wid = tid >> 6;
  int idx = blockIdx.x * 256 + tid;
  int v = (idx < NCNT) ? counts[idx] : 0;
  int orig = v;
#pragma unroll
  for (int s = 1; s < 64; s <<= 1) { int u = __shfl_up(v, s, 64); if (lane >= s) v += u; }
  __shared__ int ws[4];
  if (lane == 63) ws[wid] = v;
  __syncthreads();
  int woff = (wid > 0 ? ws[0] : 0) + (wid > 1 ? ws[1] : 0) + (wid > 2 ? ws[2] : 0);
  int excl = bsums[blockIdx.x] + woff + v - orig;
  if (idx < NCNT) {
    counts[idx] = excl;
    if (idx % NCH == 0) {
      int g = idx / NCH;  // 0..199 = t*NSL + slice
      sliceptr[(g / NSL) * (NSL + 1) + (g % NSL)] = excl;
    }
  }
  if (blockIdx.x == 0 && tid < 4) sliceptr[tid * (NSL + 1) + NSL] = (tid + 1) * EE;
}

__global__ __launch_bounds__(256) void ppart_kernel(const int* e0, const int* e1, const int* e2,
                                                    const int* e3, const int* counts, int2* pairs) {
  int t = blockIdx.y, ch = blockIdx.x;
  const int* ei = (t == 0 ? e0 : t == 1 ? e1 : t == 2 ? e2 : e3);
  const int* srcr = ei;
  const int* dstr = ei + EE;
  __shared__ int cur[NSL];
  for (int i = threadIdx.x; i < NSL; i += 256) cur[i] = counts[(t * NSL + i) * NCH + ch];
  __syncthreads();
  int i0 = ch * EPG;
  for (int i = i0 + threadIdx.x; i < i0 + EPG; i += 256) {
    int d = dstr[i], s = srcr[i];
    int pos = atomicAdd(&cur[d / SPAN], 1);
    pairs[pos] = make_int2(s, d);
  }
}

__global__ __launch_bounds__(256) void pbuild_kernel(const int2* pairs, const int* sliceptr,
                                                     int* rowptr, int* col) {
  int t = blockIdx.y, sl = blockIdx.x;
  int n0 = sl * SPAN;
  int e0 = sliceptr[t * (NSL + 1) + sl], e1 = sliceptr[t * (NSL + 1) + sl + 1];
  int tid = threadIdx.x, lane = tid & 63, wid = tid >> 6;
  __shared__ int cnt[SPAN];
  __shared__ int wsum[4];
  for (int i = tid; i < SPAN; i += 256) cnt[i] = 0;
  __syncthreads();
  for (int e = e0 + tid; e < e1; e += 256) atomicAdd(&cnt[pairs[e].y - n0], 1);
  __syncthreads();
  int s0 = 0, s1 = 0, s2 = 0, s3 = 0, tot = 0;
  if (tid < SPAN / 4) {
    s0 = cnt[tid * 4]; s1 = cnt[tid * 4 + 1]; s2 = cnt[tid * 4 + 2]; s3 = cnt[tid * 4 + 3];
    tot = s0 + s1 + s2 + s3;
  }
  int v = tot;
#pragma unroll
  for (int sft = 1; sft < 64; sft <<= 1) { int u = __shfl_up(v, sft, 64); if (lane >= sft) v += u; }
  if (lane == 63) wsum[wid] = v;
  __syncthreads();
  int woffv = (wid > 0 ? wsum[0] : 0) + (wid > 1 ? wsum[1] : 0) + (wid > 2 ? wsum[2] : 0);
  int excl = v + woffv - tot;
  __syncthreads();
  if (tid < SPAN / 4) {
    cnt[tid * 4] = excl;
    cnt[tid * 4 + 1] = excl + s0;
    cnt[tid * 4 + 2] = excl + s0 + s1;
    cnt[tid * 4 + 3] = excl + s0 + s1 + s2;
  }
  __syncthreads();
  int base = e0 - t * EE;
  for (int n = tid; n < SPAN; n += 256) rowptr[(size_t)t * (NN + 1) + n0 + n] = base + cnt[n];
  if (sl == NSL - 1 && tid == 0) rowptr[(size_t)t * (NN + 1) + NN] = EE;
  __syncthreads();
  int* ct = col + (size_t)t * EE;
  for (int e = e0 + tid; e < e1; e += 256) {
    int2 p = pairs[e];
    int pos = base + atomicAdd(&cnt[p.y - n0], 1);
    ct[pos] = p.x;
  }
}

// ---- graph boundaries via binary search on sorted batch vectors ----
__global__ void gbound_kernel(const int* batchA, const int* batchB, int* gbA, int* gbB) {
  int t = threadIdx.x;
  if (t >= 130) return;
  int which = t / 65, g = t % 65;
  const int* b = which ? batchB : batchA;
  int* gb = which ? gbB : gbA;
  int lo = 0, hi = NN;
  while (lo < hi) { int mid = (lo + hi) >> 1; if (b[mid] < g) lo = mid + 1; else hi = mid; }
  gb[g] = lo;
}

// ---- MFMA GEMM h = X @ W (split-bf16), z=4, register-prefetch pipelined.
//      XBF=false: f32 X -> hi/lo (3 MFMA terms). XBF=true: bf16 X (2 MFMA terms). ----
#define SWZ(row, kb) ((((row) << 6) + (kb)) ^ (((row) & 7) << 4))
#define HSTRIDE 136   // 272B = 17x16B: keeps epilogue rows 16B-aligned (no split reads)

__device__ __forceinline__ void cvt8(const float4 a, const float4 b, bf16x8& hv, bf16x8& lv) {
  short h;
  h = f2bf(a.x); hv[0] = h; lv[0] = f2bf(a.x - bf2f((unsigned short)h));
  h = f2bf(a.y); hv[1] = h; lv[1] = f2bf(a.y - bf2f((unsigned short)h));
  h = f2bf(a.z); hv[2] = h; lv[2] = f2bf(a.z - bf2f((unsigned short)h));
  h = f2bf(a.w); hv[3] = h; lv[3] = f2bf(a.w - bf2f((unsigned short)h));
  h = f2bf(b.x); hv[4] = h; lv[4] = f2bf(b.x - bf2f((unsigned short)h));
  h = f2bf(b.y); hv[5] = h; lv[5] = f2bf(b.y - bf2f((unsigned short)h));
  h = f2bf(b.z); hv[6] = h; lv[6] = f2bf(b.z - bf2f((unsigned short)h));
  h = f2bf(b.w); hv[7] = h; lv[7] = f2bf(b.w - bf2f((unsigned short)h));
}

template <bool XBF>
__global__ __launch_bounds__(256) void gemm_hs_kernel(
    const void* X0_, const void* X1_,
    const short* whiT, const short* wloT,   // pre-offset by L*4*16384
    const float* attsrc,                    // pre-offset by L*4*128
    unsigned short* h4, float* s4) {
  int e = blockIdx.z;
  const void* X = (e < 2) ? X0_ : X1_;   // EDGE_TYPES: e0,e1 src=A; e2,e3 src=B
  const short* Wh = whiT + (size_t)e * 16384;
  const short* Wl = wloT + (size_t)e * 16384;
  const float* att = attsrc + e * 128;
  unsigned short* h = h4 + (size_t)e * NN * 128;
  float* s_ = s4 + (size_t)e * NN;

  // 32KB pool: 4 staging planes (16384 shorts); epilogue reuses it as a 64x136 half-tile
  __shared__ short smem[16384];
  short* Ah = smem;
  short* Al = smem + 4096;
  short* Bh = smem + 8192;
  short* Bl = smem + 12288;

  int tid = threadIdx.x;
  int l = tid & 63, w = tid >> 6;
  int arow = l & 15;
  int kb = (l >> 4) << 4;
  int row0 = blockIdx.x * 128;

  f32x4 acc[2][8];
#pragma unroll
  for (int i = 0; i < 2; i++)
#pragma unroll
    for (int j = 0; j < 8; j++) acc[i][j] = (f32x4){0.f, 0.f, 0.f, 0.f};

  float attr[8];
#pragma unroll
  for (int j = 0; j < 8; j++) attr[j] = att[j * 16 + arow];

  int sr = tid >> 1, half = tid & 1;
  int xrow = row0 + sr; xrow = xrow < NN ? xrow : NN - 1;
  const float* xbaseF = nullptr;
  const short* xbaseH = nullptr;
  if constexpr (XBF) xbaseH = (const short*)X + (size_t)xrow * 128 + half * 16;
  else               xbaseF = (const float*)X + (size_t)xrow * 128 + half * 16;
  const short* whbase = Wh + sr * 128 + half * 16;
  const short* wlbase = Wl + sr * 128 + half * 16;
  int soff0 = SWZ(sr, half * 32);
  int soff1 = SWZ(sr, half * 32 + 16);

  // prologue: load tile kt=0 into registers
  float4 f0, f1, f2, f3;
  bf16x8 xh0, xh1;
  if constexpr (XBF) {
    xh0 = *(const bf16x8*)(xbaseH);
    xh1 = *(const bf16x8*)(xbaseH + 8);
  } else {
    f0 = *(const float4*)(xbaseF);
    f1 = *(const float4*)(xbaseF + 4);
    f2 = *(const float4*)(xbaseF + 8);
    f3 = *(const float4*)(xbaseF + 12);
  }
  bf16x8 wh0 = *(const bf16x8*)(whbase);
  bf16x8 wh1 = *(const bf16x8*)(whbase + 8);
  bf16x8 wl0 = *(const bf16x8*)(wlbase);
  bf16x8 wl1 = *(const bf16x8*)(wlbase + 8);

  for (int kt = 0; kt < 128; kt += 32) {
    // stage current registers -> LDS
    if constexpr (XBF) {
      *(bf16x8*)((char*)Ah + soff0) = xh0;
      *(bf16x8*)((char*)Ah + soff1) = xh1;
    } else {
      bf16x8 hv0, lv0, hv1, lv1;
      cvt8(f0, f1, hv0, lv0);
      cvt8(f2, f3, hv1, lv1);
      *(bf16x8*)((char*)Ah + soff0) = hv0;
      *(bf16x8*)((char*)Ah + soff1) = hv1;
      *(bf16x8*)((char*)Al + soff0) = lv0;
      *(bf16x8*)((char*)Al + soff1) = lv1;
    }
    *(bf16x8*)((char*)Bh + soff0) = wh0;
    *(bf16x8*)((char*)Bh + soff1) = wh1;
    *(bf16x8*)((char*)Bl + soff0) = wl0;
    *(bf16x8*)((char*)Bl + soff1) = wl1;
    __syncthreads();

    // issue next tile's global loads (latency hides under MFMA below)
    if (kt < 96) {
      if constexpr (XBF) {
        xh0 = *(const bf16x8*)(xbaseH + kt + 32);
        xh1 = *(const bf16x8*)(xbaseH + kt + 40);
      } else {
        f0 = *(const float4*)(xbaseF + kt + 32);
        f1 = *(const float4*)(xbaseF + kt + 36);
        f2 = *(const float4*)(xbaseF + kt + 40);
        f3 = *(const float4*)(xbaseF + kt + 44);
      }
      wh0 = *(const bf16x8*)(whbase + kt + 32);
      wh1 = *(const bf16x8*)(whbase + kt + 40);
      wl0 = *(const bf16x8*)(wlbase + kt + 32);
      wl1 = *(const bf16x8*)(wlbase + kt + 40);
    }

    bf16x8 ah[2], al[2];
#pragma unroll
    for (int i = 0; i < 2; i++) {
      int row = w * 32 + i * 16 + arow;
      ah[i] = *(bf16x8*)((char*)Ah + SWZ(row, kb));
      if constexpr (!XBF) al[i] = *(bf16x8*)((char*)Al + SWZ(row, kb));
    }
#pragma unroll
    for (int j = 0; j < 8; j++) {
      int colr = j * 16 + arow;
      bf16x8 bh = *(bf16x8*)((char*)Bh + SWZ(colr, kb));
      bf16x8 bl = *(bf16x8*)((char*)Bl + SWZ(colr, kb));
#pragma unroll
      for (int i = 0; i < 2; i++) {
        acc[i][j] = __builtin_amdgcn_mfma_f32_16x16x32_bf16(ah[i], bh, acc[i][j], 0, 0, 0);
        acc[i][j] = __builtin_amdgcn_mfma_f32_16x16x32_bf16(ah[i], bl, acc[i][j], 0, 0, 0);
        if constexpr (!XBF)
          acc[i][j] = __builtin_amdgcn_mfma_f32_16x16x32_bf16(al[i], bh, acc[i][j], 0, 0, 0);
      }
    }
    __syncthreads();
  }

  // epilogue in two 64-row phases (64x136 tile fits inside the 32KB staging pool):
  // waves 0,1 own rows 0..63; waves 2,3 own rows 64..127.
#pragma unroll
  for (int p = 0; p < 2; p++) {
    if ((w >> 1) == p) {
#pragma unroll
      for (int i = 0; i < 2; i++) {
#pragma unroll
        for (int r = 0; r < 4; r++) {
          int lrow = (w & 1) * 32 + i * 16 + ((l >> 4) << 2) + r;  // 0..63
          int row = row0 + p * 64 + lrow;
          float pp = 0.f;
#pragma unroll
          for (int j = 0; j < 8; j++) pp += acc[i][j][r] * attr[j];
          pp += __shfl_xor(pp, 1, 64);
          pp += __shfl_xor(pp, 2, 64);
          pp += __shfl_xor(pp, 4, 64);
          pp += __shfl_xor(pp, 8, 64);
          if (row < NN && arow == 0) s_[row] = pp;
#pragma unroll
          for (int j = 0; j < 8; j++) smem[lrow * HSTRIDE + j * 16 + arow] = f2bf(acc[i][j][r]);
        }
      }
    }
    __syncthreads();
#pragma unroll
    for (int it = 0; it < 4; it++) {
      int idx = it * 256 + tid;  // 0..1023 -> (lrow 0..63, 16B chunk)
      int lrow = idx >> 4, c8 = idx & 15;
      int row = row0 + p * 64 + lrow;
      if (row < NN)
        *(bf16x8*)(h + (size_t)row * 128 + c8 * 8) = *(const bf16x8*)(smem + lrow * HSTRIDE + c8 * 8);
    }
    __syncthreads();
  }
}

#define ACC8(a, uv, wv)                             \
  do {                                              \
    a[0] += wv * __uint_as_float(uv.x << 16);       \
    a[1] += wv * __uint_as_float(uv.x & 0xffff0000u); \
    a[2] += wv * __uint_as_float(uv.y << 16);       \
    a[3] += wv * __uint_as_float(uv.y & 0xffff0000u); \
    a[4] += wv * __uint_as_float(uv.z << 16);       \
    a[5] += wv * __uint_as_float(uv.z & 0xffff0000u); \
    a[6] += wv * __uint_as_float(uv.w << 16);       \
    a[7] += wv * __uint_as_float(uv.w & 0xffff0000u); \
  } while (0)

// ---- per-dst-node GAT aggregation: TWO 16-lane groups per node (one per edge type);
//      single pass (exp(s) directly), 4-wide gather unroll, cross-group combine.
//      XBF: xdst stored bf16. Y always written bf16. ----
template <bool XBF>
__global__ __launch_bounds__(256) void agg_kernel(
    const void* xdst_,
    const int* rpA, const int* colA, const unsigned short* hA_, const float* sA_, const float* vA, const float* bA,
    const int* rpB, const int* colB, const unsigned short* hB_, const float* sB_, const float* vB, const float* bB,
    unsigned short* Y) {
  int lane = threadIdx.x & 63;
  int q = lane & 15;             // lane within group
  int gb = lane & 48;            // group base within wave (for shfl)
  int t = (lane >> 4) & 1;       // group parity -> edge type half
  int node = blockIdx.x * 8 + (threadIdx.x >> 5);
  if (node >= NN) return;
  int d0 = q * 8;
  float4 xv0, xv1;
  if constexpr (XBF) {
    const unsigned short* xr = (const unsigned short*)xdst_ + (size_t)node * 128 + d0;
    uint4 u = *(const uint4*)xr;
    xv0 = make_float4(__uint_as_float(u.x << 16), __uint_as_float(u.x & 0xffff0000u),
                      __uint_as_float(u.y << 16), __uint_as_float(u.y & 0xffff0000u));
    xv1 = make_float4(__uint_as_float(u.z << 16), __uint_as_float(u.z & 0xffff0000u),
                      __uint_as_float(u.w << 16), __uint_as_float(u.w & 0xffff0000u));
  } else {
    const float* xr = (const float*)xdst_ + (size_t)node * 128 + d0;
    xv0 = *(const float4*)(xr);
    xv1 = *(const float4*)(xr + 4);
  }

  const int* rp = t ? rpB : rpA;
  const int* cl = t ? colB : colA;
  const unsigned short* h = t ? hB_ : hA_;
  const float* ss = t ? sB_ : sA_;
  const float* v = t ? vB : vA;
  const float* b = t ? bB : bA;
  const uint4* hq = (const uint4*)h + q;  // lane's 16B slice of each row

  float4 v0 = *(const float4*)(v + d0);
  float4 v1 = *(const float4*)(v + d0 + 4);
  float part = xv0.x * v0.x + xv0.y * v0.y + xv0.z * v0.z + xv0.w * v0.w +
               xv1.x * v1.x + xv1.y * v1.y + xv1.z * v1.z + xv1.w * v1.w;
  float sd = gred_sum(part);

  int start = rp[node], end = rp[node + 1];
  int deg = end - start;

  float dsum = 0.f;
  float a[8] = {0.f, 0.f, 0.f, 0.f, 0.f, 0.f, 0.f, 0.f};

  for (int base2 = start; base2 < end; base2 += 16) {
    int i = base2 + q;
    int src = 0;
    float ex = 0.f;
    if (i < end) {
      src = cl[i];
      float s = ss[src] + sd;
      s = (s >= 0.f) ? s : 0.2f * s;
      ex = __expf(s);
    }
    dsum += ex;
    int cT = min(16, end - base2);
    int j = 0;
    for (; j + 3 < cT; j += 4) {
      int sj0 = __shfl(src, gb + j, 64);     float e0 = __shfl(ex, gb + j, 64);
      int sj1 = __shfl(src, gb + j + 1, 64); float e1 = __shfl(ex, gb + j + 1, 64);
      int sj2 = __shfl(src, gb + j + 2, 64); float e2 = __shfl(ex, gb + j + 2, 64);
      int sj3 = __shfl(src, gb + j + 3, 64); float e3 = __shfl(ex, gb + j + 3, 64);
      uint4 uv0 = hq[(size_t)sj0 * 16];
      uint4 uv1 = hq[(size_t)sj1 * 16];
      uint4 uv2 = hq[(size_t)sj2 * 16];
      uint4 uv3 = hq[(size_t)sj3 * 16];
      ACC8(a, uv0, e0);
      ACC8(a, uv1, e1);
      ACC8(a, uv2, e2);
      ACC8(a, uv3, e3);
    }
    for (; j < cT; j++) {
      int sj = __shfl(src, gb + j, 64);
      float ej = __shfl(ex, gb + j, 64);
      uint4 uv = hq[(size_t)sj * 16];
      ACC8(a, uv, ej);
    }
  }

  float denom = gred_sum(dsum);
  float inv = (deg > 0) ? 0.5f / (denom * (float)deg) : 0.f;
  float outv[8];
#pragma unroll
  for (int k2 = 0; k2 < 8; k2++) outv[k2] = a[k2] * inv + 0.5f * b[d0 + k2];

  // combine the two edge-type groups of this node (lanes x and x^16)
#pragma unroll
  for (int k2 = 0; k2 < 8; k2++) outv[k2] += __shfl_xor(outv[k2], 16, 64);

  if (!(lane & 16)) {
    bf16x8 o;
#pragma unroll
    for (int k2 = 0; k2 < 8; k2++) o[k2] = f2bf(fmaxf(outv[k2], 0.f));
    *(bf16x8*)(Y + (size_t)node * 128 + d0) = o;
  }
}

// ---- mean pooling stage 1 (bf16 input): partial sums, 8 chunks per (graph, type) ----
__global__ __launch_bounds__(64) void pool_part_kernel(const unsigned short* XA_, const unsigned short* XB_,
                                                       const int* gbA, const int* gbB,
                                                       float* pooled) {
  int t = blockIdx.y, g = blockIdx.x, c = blockIdx.z;
  const unsigned short* X = t ? XB_ : XA_;
  const int* gb = t ? gbB : gbA;
  int n0 = gb[g], n1 = gb[g + 1];
  int d = threadIdx.x * 2;  // dim pair
  float s0 = 0.f, s1 = 0.f;
  for (int node = n0 + c; node < n1; node += 8) {
    unsigned int u = *(const unsigned int*)(X + (size_t)node * 128 + d);
    s0 += __uint_as_float(u << 16);
    s1 += __uint_as_float(u & 0xffff0000u);
  }
  atomicAdd(&pooled[g * 256 + t * 128 + d], s0);
  atomicAdd(&pooled[g * 256 + t * 128 + d + 1], s1);
}

// ---- final linear (divides pooled sums by counts) ----
__global__ void final_kernel(const float* pooled, const int* gbA, const int* gbB,
                             const float* wc, const float* bc, float* out) {
  int tid = blockIdx.x * blockDim.x + threadIdx.x;
  if (tid >= GG * 10) return;
  int g = tid / 10, o = tid % 10;
  float invA = 1.f / fmaxf((float)(gbA[g + 1] - gbA[g]), 1.f);
  float invB = 1.f / fmaxf((float)(gbB[g + 1] - gbB[g]), 1.f);
  float acc = bc[o];
  for (int k = 0; k < 256; k++)
    acc += pooled[g * 256 + k] * (k < 128 ? invA : invB) * wc[k * 10 + o];
  out[g * 10 + o] = acc;
}

extern "C" void kernel_launch(void* const* d_in, const int* in_sizes, int n_in,
                              void* d_out, int out_size, void* d_ws, size_t ws_size,
                              hipStream_t stream) {
  const float* xA = (const float*)d_in[0];
  const float* xB = (const float*)d_in[1];
  const int* ei0 = (const int*)d_in[2];
  const int* ei1 = (const int*)d_in[3];
  const int* ei2 = (const int*)d_in[4];
  const int* ei3 = (const int*)d_in[5];
  const int* batchA = (const int*)d_in[6];
  const int* batchB = (const int*)d_in[7];
  const float* wsrc = (const float*)d_in[9];
  const float* wdst = (const float*)d_in[10];
  const float* attsrc = (const float*)d_in[11];
  const float* attdst = (const float*)d_in[12];
  const float* cbias = (const float*)d_in[13];
  const float* wc = (const float*)d_in[14];
  const float* bc = (const float*)d_in[15];
  float* out = (float*)d_out;

  char* ws = (char*)d_ws;
  size_t off = 0;
  auto alloc = [&](size_t bytes) { size_t o = off; off += (bytes + 255) & ~(size_t)255; return o; };
  size_t o_rowptr = alloc((size_t)4 * (NN + 1) * 4);
  size_t o_col    = alloc((size_t)4 * EE * 4);
  size_t o_cnts   = alloc((size_t)NCNT * 4);
  size_t o_bsums  = alloc((size_t)SCB * 4);
  size_t o_slptr  = alloc((size_t)4 * (NSL + 1) * 4);
  size_t o_v      = alloc((size_t)8 * 128 * 4);
  size_t o_whiT   = alloc((size_t)8 * 16384 * 2);
  size_t o_wloT   = alloc((size_t)8 * 16384 * 2);
  size_t o_h4     = alloc((size_t)4 * NN * 128 * 2);  // bf16 h per edge type; pairs alias pre-GEMM
  size_t o_s4     = alloc((size_t)4 * NN * 4);
  size_t o_Xa1    = alloc((size_t)NN * 128 * 2);      // bf16 inter-layer activations
  size_t o_Xb1    = alloc((size_t)NN * 128 * 2);
  size_t o_Xa2    = alloc((size_t)NN * 128 * 2);
  size_t o_Xb2    = alloc((size_t)NN * 128 * 2);
  size_t o_pooled = alloc((size_t)GG * 256 * 4);
  size_t o_gb     = alloc((size_t)2 * (GG + 1) * 4);

  int* rowptr = (int*)(ws + o_rowptr);
  int* col = (int*)(ws + o_col);
  int* counts = (int*)(ws + o_cnts);
  int* bsums = (int*)(ws + o_bsums);
  int* sliceptr = (int*)(ws + o_slptr);
  float* vv = (float*)(ws + o_v);
  short* whiT = (short*)(ws + o_whiT);
  short* wloT = (short*)(ws + o_wloT);
  unsigned short* h4 = (unsigned short*)(ws + o_h4);
  float* s4 = (float*)(ws + o_s4);
  int2* pairs = (int2*)(ws + o_h4);  // 16 MB alias over h4 (dead until GEMMs)
  unsigned short* Xa1 = (unsigned short*)(ws + o_Xa1);
  unsigned short* Xb1 = (unsigned short*)(ws + o_Xb1);
  unsigned short* Xa2 = (unsigned short*)(ws + o_Xa2);
  unsigned short* Xb2 = (unsigned short*)(ws + o_Xb2);
  float* pooled = (float*)(ws + o_pooled);
  int* gbA = (int*)(ws + o_gb);
  int* gbB = gbA + (GG + 1);

  hipMemsetAsync(pooled, 0, (size_t)GG * 256 * 4, stream);

  v_kernel<<<256, 256, 0, stream>>>(wdst, attdst, vv);
  wcvt_kernel<<<512, 256, 0, stream>>>(wsrc, whiT, wloT);
  gbound_kernel<<<1, 192, 0, stream>>>(batchA, batchB, gbA, gbB);
  pcount_kernel<<<dim3(NCH, 4), 256, 0, stream>>>(ei0, ei1, ei2, ei3, counts);
  scan1_kernel<<<SCB, 256, 0, stream>>>(counts, bsums);
  scan2_kernel<<<1, 128, 0, stream>>>(bsums);
  scan3_kernel<<<SCB, 256, 0, stream>>>(counts, bsums, sliceptr);
  ppart_kernel<<<dim3(NCH, 4), 256, 0, stream>>>(ei0, ei1, ei2, ei3, counts, pairs);
  pbuild_kernel<<<dim3(NSL, 4), 256, 0, stream>>>(pairs, sliceptr, rowptr, col);

  int gemm_gx = (NN + 127) / 128;
  int agg_gx = (NN + 7) / 8;

  for (int L = 0; L < 2; L++) {
    // all 4 edge-type GEMMs of this layer in one z=4 launch
    if (L == 0)
      gemm_hs_kernel<false><<<dim3(gemm_gx, 1, 4), 256, 0, stream>>>(
          xA, xB, whiT, wloT, attsrc, h4, s4);
    else
      gemm_hs_kernel<true><<<dim3(gemm_gx, 1, 4), 256, 0, stream>>>(
          Xa1, Xb1, whiT + (size_t)4 * 16384, wloT + (size_t)4 * 16384,
          attsrc + 4 * 128, h4, s4);

    unsigned short* Y0 = (L == 0) ? Xa1 : Xa2;
    unsigned short* Y1 = (L == 0) ? Xb1 : Xb2;
    const float* vvL = vv + L * 4 * 128;
    const float* cbL = cbias + L * 4 * 128;

    // dst type 0: edge types 0 (src=A) and 2 (src=B)
    if (L == 0)
      agg_kernel<false><<<agg_gx, 256, 0, stream>>>(
          xA,
          rowptr + (size_t)0 * (NN + 1), col + (size_t)0 * EE, h4 + (size_t)0 * NN * 128, s4 + (size_t)0 * NN,
          vvL + 0 * 128, cbL + 0 * 128,
          rowptr + (size_t)2 * (NN + 1), col + (size_t)2 * EE, h4 + (size_t)2 * NN * 128, s4 + (size_t)2 * NN,
          vvL + 2 * 128, cbL + 2 * 128, Y0);
    else
      agg_kernel<true><<<agg_gx, 256, 0, stream>>>(
          Xa1,
          rowptr + (size_t)0 * (NN + 1), col + (size_t)0 * EE, h4 + (size_t)0 * NN * 128, s4 + (size_t)0 * NN,
          vvL + 0 * 128, cbL + 0 * 128,
          rowptr + (size_t)2 * (NN + 1), col + (size_t)2 * EE, h4 + (size_t)2 * NN * 128, s4 + (size_t)2 * NN,
          vvL + 2 * 128, cbL + 2 * 128, Y0);

    // dst type 1: edge types 1 (src=A) and 3 (src=B)
    if (L == 0)
      agg_kernel<false><<<agg_gx, 256, 0, stream>>>(
          xB,
          rowptr + (size_t)1 * (NN + 1), col + (size_t)1 * EE, h4 + (size_t)1 * NN * 128, s4 + (size_t)1 * NN,
          vvL + 1 * 128, cbL + 1 * 128,
          rowptr + (size_t)3 * (NN + 1), col + (size_t)3 * EE, h4 + (size_t)3 * NN * 128, s4 + (size_t)3 * NN,
          vvL + 3 * 128, cbL + 3 * 128, Y1);
    else
      agg_kernel<true><<<agg_gx, 256, 0, stream>>>(
          Xb1,
          rowptr + (size_t)1 * (NN + 1), col + (size_t)1 * EE, h4 + (size_t)1 * NN * 128, s4 + (size_t)1 * NN,
          vvL + 1 * 128, cbL + 1 * 128,
          rowptr + (size_t)3 * (NN + 1), col + (size_t)3 * EE, h4 + (size_t)3 * NN * 128, s4 + (size_t)3 * NN,
          vvL + 3 * 128, cbL + 3 * 128, Y1);
  }

  pool_part_kernel<<<dim3(GG, 2, 8), 64, 0, stream>>>(Xa2, Xb2, gbA, gbB, pooled);
  final_kernel<<<3, 256, 0, stream>>>(pooled, gbA, gbB, wc, bc, out);
}